// Round 4
// baseline (330.934 us; speedup 1.0000x reference)
//
#include <hip/hip_runtime.h>
#include <stdint.h>

// ---------- types ----------
typedef __attribute__((ext_vector_type(8))) short  short8;   // 8 bf16 (4 VGPRs)
typedef __attribute__((ext_vector_type(4))) float  f32x4;
typedef __attribute__((ext_vector_type(4))) float  float4v;
typedef __attribute__((ext_vector_type(4))) unsigned short ushort4v;

#define DEV __device__ __forceinline__

// ---------- bf16 helpers (RNE) ----------
DEV unsigned short f2bf(float f) {
    union { float f; unsigned int u; } x; x.f = f;
    unsigned int u = x.u;
    unsigned int r = (u + 0x7fffu + ((u >> 16) & 1u)) >> 16;
    return (unsigned short)r;
}
DEV float bf2f(unsigned short b) {
    union { unsigned int u; float f; } x; x.u = ((unsigned int)b) << 16;
    return x.f;
}

// ---------- async global->LDS, 16B/lane ----------
DEV void gll16(const void* g, void* l) {
    __builtin_amdgcn_global_load_lds(
        (const __attribute__((address_space(1))) void*)g,
        (__attribute__((address_space(3))) void*)l, 16, 0, 0);
}

// ---------- problem constants ----------
#define MROWS 4096
#define KDIM  2048
#define NQK   4096

// ============================================================
// elementwise f32 -> bf16 cast
// ============================================================
__global__ void cast_f32_bf16(const float* __restrict__ in,
                              unsigned short* __restrict__ out, int n4) {
    int i = blockIdx.x * blockDim.x + threadIdx.x;
    if (i < n4) {
        float4v f = ((const float4v*)in)[i];
        ushort4v o;
        o[0] = f2bf(f[0]); o[1] = f2bf(f[1]); o[2] = f2bf(f[2]); o[3] = f2bf(f[3]);
        ((ushort4v*)out)[i] = o;
    }
}

// ============================================================
// transpose + cast: W (K x N, f32) -> Wt (N x K, bf16)
// ============================================================
__global__ void transpose_cast(const float* __restrict__ W,
                               unsigned short* __restrict__ Wt, int K, int N) {
    __shared__ float tile[32][33];
    int tx = threadIdx.x, ty = threadIdx.y;
    int n0 = blockIdx.x * 32, k0 = blockIdx.y * 32;
#pragma unroll
    for (int j = 0; j < 32; j += 8)
        tile[ty + j][tx] = W[(size_t)(k0 + ty + j) * N + n0 + tx];
    __syncthreads();
#pragma unroll
    for (int j = 0; j < 32; j += 8)
        Wt[(size_t)(n0 + ty + j) * K + k0 + tx] = f2bf(tile[tx][ty + j]);
}

// ============================================================
// bf16 transpose: vp [4096 t][2048 (h d)] -> vpT [64 bh][128 d][1024 t]
// ============================================================
__global__ void transpose_v(const unsigned short* __restrict__ vp,
                            unsigned short* __restrict__ vpT) {
    __shared__ unsigned short tile[32][34];
    int tx = threadIdx.x, ty = threadIdx.y;
    int R0 = blockIdx.y * 32;
    int c0 = blockIdx.x * 32;
    int bh = R0 >> 7, d0 = R0 & 127;
    int b = bh >> 4, h = bh & 15;
#pragma unroll
    for (int j = 0; j < 32; j += 8)
        tile[ty + j][tx] = vp[(size_t)(b * 1024 + c0 + ty + j) * 2048 + h * 128 + d0 + tx];
    __syncthreads();
#pragma unroll
    for (int j = 0; j < 32; j += 8)
        vpT[(size_t)(R0 + ty + j) * 1024 + c0 + tx] = tile[tx][ty + j];
}

// ============================================================
// 256x256-tile 8-phase GEMM, software-pipelined fragments.
//   C[M x N] = A[M x K] * Bt[N x K]^T, bf16 in, f32 acc.
// 512 threads = 8 waves (2M x 4N); per-wave 128x64 output.
// BK=64; LDS 128 KiB double-buffered.
// Fragment pipeline: q0 reads BC(8)+Ra(4)+Rb-prefetch(4), lgkmcnt(4);
// q1 prefetches afr(2) into Ra, lgkmcnt(4) (pre-satisfied);
// q2 prefetches afr(3) into Rb; q3 reads nothing. Prefetched reads
// drain UNDER the current phase's MFMA instead of stalling the next.
// vmcnt: only q3 tail (4 in steady state -> B(u+2) stays in flight).
// XCD chunk swizzle on block ids (nwg % 8 == 0 for all launches).
// ============================================================
__global__ __launch_bounds__(512, 2) void gemm256(
    const unsigned short* __restrict__ A0g, const unsigned short* __restrict__ B0g,
    float* __restrict__ Cf0, unsigned short* __restrict__ Ch0,
    int N0, int tx0, int nb0, int outbf0,
    const unsigned short* __restrict__ A1g, const unsigned short* __restrict__ B1g,
    float* __restrict__ Cf1, unsigned short* __restrict__ Ch1,
    int N1, int tx1, int outbf1, int K) {

    __shared__ __align__(16) char lds[131072];

    int blk = blockIdx.x;
    const unsigned short* Ag; const unsigned short* Bg;
    float* Cf; unsigned short* Ch; int N, tx, outbf, nwg;
    if (blk < nb0) { Ag = A0g; Bg = B0g; Cf = Cf0; Ch = Ch0; N = N0; tx = tx0; outbf = outbf0; nwg = nb0; }
    else { blk -= nb0; Ag = A1g; Bg = B1g; Cf = Cf1; Ch = Ch1; N = N1; tx = tx1; outbf = outbf1; nwg = gridDim.x - nb0; }
    // T1: XCD chunk swizzle (bijective; nwg % 8 == 0)
    { int cpx = nwg >> 3; blk = (blk & 7) * cpx + (blk >> 3); }
    const int bx = blk % tx, by = blk / tx;

    const int tid = threadIdx.x;
    const int lane = tid & 63;
    const int w  = tid >> 6;
    const int lr = lane & 15, lk = lane >> 4;
    const int wm = w >> 2, wn = w & 3;
    const int cswz16 = (lk ^ ((lr >> 3) << 1)) * 16;   // swizzled 16B-chunk offset

    const unsigned short* Arow = Ag + (size_t)(by * 256) * K;
    const unsigned short* Brow = Bg + (size_t)(bx * 256) * K;

    // stage one half-tile (128 rows x 64 cols) : 2 x gll16 per thread
    auto STAGE = [&](const unsigned short* srcHalf, int k0, char* ldsHalf) {
        int row  = tid >> 2;
        int clog = (tid & 3) ^ (((tid >> 5) & 1) << 1);   // source pre-swizzle
        const unsigned short* g = srcHalf + (size_t)row * K + k0 + clog * 8;
        gll16(g,      ldsHalf + tid * 16);            // ks=0 panel
        gll16(g + 32, ldsHalf + 8192 + tid * 16);     // ks=1 panel
    };

    f32x4 acc[8][4];
#pragma unroll
    for (int m = 0; m < 8; ++m)
#pragma unroll
        for (int n = 0; n < 4; ++n) acc[m][n] = (f32x4){0.f, 0.f, 0.f, 0.f};

    const int NT = K >> 6;   // 32
    char* buf0 = lds;
    char* buf1 = lds + 65536;

    // ---- prologue: B(0), A(0), B(1); leave B(1) in flight ----
    STAGE(Brow,                   0, buf0 + 32768);
    STAGE(Brow + (size_t)128 * K, 0, buf0 + 32768 + 16384);
    STAGE(Arow,                   0, buf0);
    STAGE(Arow + (size_t)128 * K, 0, buf0 + 16384);
    STAGE(Brow,                  64, buf1 + 32768);
    STAGE(Brow + (size_t)128 * K, 64, buf1 + 32768 + 16384);
    asm volatile("s_waitcnt vmcnt(4)" ::: "memory");
    __builtin_amdgcn_s_barrier();

#define MFMA_BF(a, b, c) __builtin_amdgcn_mfma_f32_16x16x32_bf16(a, b, c, 0, 0, 0)

    // load A fragments for phase P (rows 32P..32P+31, both ks panels)
#define LDAFR(DST, P)                                                                \
    DST[0] = *(const short8*)(aBase +        ((P) * 32 +      lr) * 64 + cswz16);    \
    DST[1] = *(const short8*)(aBase + 8192 + ((P) * 32 +      lr) * 64 + cswz16);    \
    DST[2] = *(const short8*)(aBase +        ((P) * 32 + 16 + lr) * 64 + cswz16);    \
    DST[3] = *(const short8*)(aBase + 8192 + ((P) * 32 + 16 + lr) * 64 + cswz16);

    // 16 MFMA for phase P using fragment set R (8 independent, then 8 dependent)
#define MFMA16(P, R)                                                       \
    __builtin_amdgcn_s_setprio(1);                                         \
    _Pragma("unroll")                                                      \
    for (int nf = 0; nf < 4; ++nf) {                                       \
        acc[2*(P)][nf]   = MFMA_BF(R[0], BC[nf][0], acc[2*(P)][nf]);       \
        acc[2*(P)+1][nf] = MFMA_BF(R[2], BC[nf][0], acc[2*(P)+1][nf]);     \
    }                                                                      \
    _Pragma("unroll")                                                      \
    for (int nf = 0; nf < 4; ++nf) {                                       \
        acc[2*(P)][nf]   = MFMA_BF(R[1], BC[nf][1], acc[2*(P)][nf]);       \
        acc[2*(P)+1][nf] = MFMA_BF(R[3], BC[nf][1], acc[2*(P)+1][nf]);     \
    }                                                                      \
    __builtin_amdgcn_s_setprio(0);

    for (int u = 0; u < NT; ++u) {
        char* bufC = (u & 1) ? buf1 : buf0;
        char* bufN = (u & 1) ? buf0 : buf1;
        const char* aBase = bufC + wm * 16384;
        const char* bBase = bufC + 32768 + (wn >> 1) * 16384;
        const int bRow0 = (wn & 1) * 64;
        const bool stA = (u + 1 < NT), stB = (u + 2 < NT);

        // ---- q0: BC + afr(0) + afr(1) prefetch ----
        short8 BC[4][2];
#pragma unroll
        for (int nf = 0; nf < 4; ++nf) {
            BC[nf][0] = *(const short8*)(bBase +        (bRow0 + nf * 16 + lr) * 64 + cswz16);
            BC[nf][1] = *(const short8*)(bBase + 8192 + (bRow0 + nf * 16 + lr) * 64 + cswz16);
        }
        short8 Ra[4], Rb[4];
        LDAFR(Ra, 0)
        LDAFR(Rb, 1)                                   // prefetch: drains under q0 MFMA
        if (stA) STAGE(Arow, (u + 1) * 64, bufN);
        asm volatile("s_waitcnt lgkmcnt(4)" ::: "memory");   // BC + afr(0) done
        __builtin_amdgcn_s_barrier();
        MFMA16(0, Ra)
        __builtin_amdgcn_s_barrier();

        // ---- q1: afr(2) prefetch ----
        LDAFR(Ra, 2)
        if (stA) STAGE(Arow + (size_t)128 * K, (u + 1) * 64, bufN + 16384);
        asm volatile("s_waitcnt lgkmcnt(4)" ::: "memory");   // afr(1) done (pre-satisfied)
        __builtin_amdgcn_s_barrier();
        MFMA16(1, Rb)
        __builtin_amdgcn_s_barrier();

        // ---- q2: afr(3) prefetch ----
        LDAFR(Rb, 3)
        if (stB) STAGE(Brow, (u + 2) * 64, bufC + 32768);
        asm volatile("s_waitcnt lgkmcnt(4)" ::: "memory");   // afr(2) done (pre-satisfied)
        __builtin_amdgcn_s_barrier();
        MFMA16(2, Ra)
        __builtin_amdgcn_s_barrier();

        // ---- q3: no fragment reads ----
        if (stB) STAGE(Brow + (size_t)128 * K, (u + 2) * 64, bufC + 32768 + 16384);
        asm volatile("s_waitcnt lgkmcnt(0)" ::: "memory");   // afr(3) done (pre-satisfied)
        __builtin_amdgcn_s_barrier();
        MFMA16(3, Rb)
        if (stB) { asm volatile("s_waitcnt vmcnt(4)" ::: "memory"); }  // drain B(u+1),A(u+1)
        else     { asm volatile("s_waitcnt vmcnt(0)" ::: "memory"); }
        __builtin_amdgcn_s_barrier();
    }
#undef LDAFR
#undef MFMA16

    // ---- epilogue: C/D layout col = lane&15, row = (lane>>4)*4 + reg ----
    if (outbf) {
#pragma unroll
        for (int mf = 0; mf < 8; ++mf)
#pragma unroll
            for (int nf = 0; nf < 4; ++nf)
#pragma unroll
                for (int r = 0; r < 4; ++r) {
                    int row = by * 256 + wm * 128 + mf * 16 + lk * 4 + r;
                    int col = bx * 256 + wn * 64 + nf * 16 + lr;
                    Ch[(size_t)row * N + col] = f2bf(acc[mf][nf][r]);
                }
    } else {
#pragma unroll
        for (int mf = 0; mf < 8; ++mf)
#pragma unroll
            for (int nf = 0; nf < 4; ++nf)
#pragma unroll
                for (int r = 0; r < 4; ++r) {
                    int row = by * 256 + wm * 128 + mf * 16 + lk * 4 + r;
                    int col = bx * 256 + wn * 64 + nf * 16 + lr;
                    Cf[(size_t)row * N + col] = acc[mf][nf][r];
                }
    }
}

// ============================================================
// RoPE in-place on qk16 (4096 x 4096 bf16)
// ============================================================
__global__ void rope_kernel(unsigned short* __restrict__ qk,
                            const float* __restrict__ fcos,
                            const float* __restrict__ fsin) {
    int idx  = blockIdx.x * 256 + threadIdx.x;
    int row  = idx >> 9;
    int g    = idx & 511;
    int t    = row & 1023;
    int half = g >> 8;
    int hp   = g & 255;
    int h    = hp >> 4;
    int ig   = hp & 15;
    int col  = half * 2048 + h * 128 + ig * 8;
    size_t off = (size_t)row * 4096 + col;

    short8 v = *(short8*)(qk + off);
    int i0 = ig * 4;
    float4v c = *(const float4v*)(fcos + t * 64 + i0);
    float4v s = *(const float4v*)(fsin + t * 64 + i0);
    short8 o;
#pragma unroll
    for (int p = 0; p < 4; ++p) {
        float re = bf2f((unsigned short)v[2 * p]);
        float im = bf2f((unsigned short)v[2 * p + 1]);
        o[2 * p]     = (short)f2bf(re * c[p] - im * s[p]);
        o[2 * p + 1] = (short)f2bf(re * s[p] + im * c[p]);
    }
    *(short8*)(qk + off) = o;
}

// ============================================================
// Flash-style causal attention (unchanged)
// ============================================================
__global__ __launch_bounds__(256) void attn_kernel(
    const unsigned short* __restrict__ qk,
    const unsigned short* __restrict__ vpT,
    unsigned short* __restrict__ y) {

    const int bh = blockIdx.x;
    const int qt = 7 - (int)blockIdx.y;
    const int b = bh >> 4, h = bh & 15;
    const int qb0 = qt * 128;

    __shared__ __align__(16) unsigned short Kt[64 * 128];
    __shared__ __align__(16) unsigned short Vt[128 * 64];
    __shared__ __align__(16) unsigned short Pl[4 * 32 * 72];

    const int tid = threadIdx.x, w = tid >> 6, lane = tid & 63;
    const int lr = lane & 15, lk = lane >> 4;

    const unsigned short* Qb = qk + (size_t)(b * 1024) * 4096 + h * 128;
    const unsigned short* Kb = Qb + 2048;
    const unsigned short* Vg = vpT + (size_t)bh * 128 * 1024;
    unsigned short* Pw = &Pl[w * 32 * 72];

    short8 qf[2][4];
#pragma unroll
    for (int m = 0; m < 2; ++m) {
        const unsigned short* qrow = Qb + (size_t)(qb0 + w * 32 + m * 16 + lr) * 4096;
#pragma unroll
        for (int db = 0; db < 4; ++db)
            qf[m][db] = *(const short8*)(qrow + db * 32 + lk * 8);
    }

    f32x4 acc[2][8];
#pragma unroll
    for (int m = 0; m < 2; ++m)
#pragma unroll
        for (int n = 0; n < 8; ++n) acc[m][n] = (f32x4){0.f, 0.f, 0.f, 0.f};
    float m_i[2][4], l_i[2][4];
#pragma unroll
    for (int m = 0; m < 2; ++m)
#pragma unroll
        for (int r = 0; r < 4; ++r) { m_i[m][r] = -1e30f; l_i[m][r] = 0.f; }

    const int nkt = 2 * qt + 2;
    for (int kt = 0; kt < nkt; ++kt) {
#pragma unroll
        for (int c = 0; c < 4; ++c) {
            int base = w * 4096 + c * 1024;
            int row  = (base >> 8) + (lane >> 4);
            int colB = (lane & 15) * 16;
            int scol = colB ^ ((row & 7) << 4);
            gll16(Kb + (size_t)(kt * 64 + row) * 4096 + (scol >> 1),
                  (char*)Kt + base);
        }
#pragma unroll
        for (int c = 0; c < 4; ++c) {
            int base = w * 4096 + c * 1024;
            int d    = (base >> 7) + (lane >> 3);
            int colB = (lane & 7) * 16;
            int scol = colB ^ ((d & 7) << 4);
            gll16(Vg + (size_t)d * 1024 + kt * 64 + (scol >> 1),
                  (char*)Vt + base);
        }
        __syncthreads();

        f32x4 s[2][4];
#pragma unroll
        for (int m = 0; m < 2; ++m)
#pragma unroll
            for (int n = 0; n < 4; ++n) s[m][n] = (f32x4){0.f, 0.f, 0.f, 0.f};
#pragma unroll
        for (int db = 0; db < 4; ++db)
#pragma unroll
            for (int n = 0; n < 4; ++n) {
                int krow = n * 16 + lr;
                int cb = (db * 64 + lk * 16) ^ ((krow & 7) << 4);
                short8 kf = *(const short8*)((const char*)Kt + krow * 256 + cb);
                s[0][n] = __builtin_amdgcn_mfma_f32_16x16x32_bf16(qf[0][db], kf, s[0][n], 0, 0, 0);
                s[1][n] = __builtin_amdgcn_mfma_f32_16x16x32_bf16(qf[1][db], kf, s[1][n], 0, 0, 0);
            }

        const float sc = 0.08838834764831845f;
        const bool diag = (kt >= 2 * qt);
#pragma unroll
        for (int m = 0; m < 2; ++m)
#pragma unroll
            for (int n = 0; n < 4; ++n)
#pragma unroll
                for (int r = 0; r < 4; ++r) {
                    float v = s[m][n][r] * sc;
                    if (diag) {
                        int q   = qb0 + w * 32 + m * 16 + lk * 4 + r;
                        int key = kt * 64 + n * 16 + lr;
                        if (key > q) v = -1e30f;
                    }
                    s[m][n][r] = v;
                }

#pragma unroll
        for (int m = 0; m < 2; ++m) {
            float pm[4];
#pragma unroll
            for (int r = 0; r < 4; ++r)
                pm[r] = fmaxf(fmaxf(s[m][0][r], s[m][1][r]), fmaxf(s[m][2][r], s[m][3][r]));
#pragma unroll
            for (int o = 1; o < 16; o <<= 1)
#pragma unroll
                for (int r = 0; r < 4; ++r)
                    pm[r] = fmaxf(pm[r], __shfl_xor(pm[r], o, 16));

            float resc[4], rs[4];
#pragma unroll
            for (int r = 0; r < 4; ++r) {
                float mn = fmaxf(m_i[m][r], pm[r]);
                resc[r] = __expf(m_i[m][r] - mn);
                m_i[m][r] = mn;
                rs[r] = 0.f;
            }
#pragma unroll
            for (int n = 0; n < 4; ++n)
#pragma unroll
                for (int r = 0; r < 4; ++r) {
                    float p = __expf(s[m][n][r] - m_i[m][r]);
                    s[m][n][r] = p;
                    rs[r] += p;
                }
#pragma unroll
            for (int o = 1; o < 16; o <<= 1)
#pragma unroll
                for (int r = 0; r < 4; ++r)
                    rs[r] += __shfl_xor(rs[r], o, 16);
#pragma unroll
            for (int r = 0; r < 4; ++r)
                l_i[m][r] = l_i[m][r] * resc[r] + rs[r];
#pragma unroll
            for (int n = 0; n < 8; ++n)
#pragma unroll
                for (int r = 0; r < 4; ++r)
                    acc[m][n][r] *= resc[r];

#pragma unroll
            for (int n = 0; n < 4; ++n)
#pragma unroll
                for (int r = 0; r < 4; ++r)
                    Pw[(m * 16 + lk * 4 + r) * 72 + n * 16 + lr] = f2bf(s[m][n][r]);
        }

#pragma unroll
        for (int ks = 0; ks < 2; ++ks) {
            short8 pf0 = *(const short8*)&Pw[(lr) * 72 + ks * 32 + lk * 8];
            short8 pf1 = *(const short8*)&Pw[(16 + lr) * 72 + ks * 32 + lk * 8];
#pragma unroll
            for (int n8 = 0; n8 < 8; ++n8) {
                int d  = n8 * 16 + lr;
                int cb = (ks * 64 + lk * 16) ^ ((d & 7) << 4);
                short8 vf = *(const short8*)((const char*)Vt + d * 128 + cb);
                acc[0][n8] = __builtin_amdgcn_mfma_f32_16x16x32_bf16(pf0, vf, acc[0][n8], 0, 0, 0);
                acc[1][n8] = __builtin_amdgcn_mfma_f32_16x16x32_bf16(pf1, vf, acc[1][n8], 0, 0, 0);
            }
        }
        __syncthreads();
    }

    unsigned short* yb = y + (size_t)(b * 1024) * 2048 + h * 128;
#pragma unroll
    for (int m = 0; m < 2; ++m)
#pragma unroll
        for (int n8 = 0; n8 < 8; ++n8)
#pragma unroll
            for (int r = 0; r < 4; ++r) {
                int t = qb0 + w * 32 + m * 16 + lk * 4 + r;
                int d = n8 * 16 + lr;
                yb[(size_t)t * 2048 + d] = f2bf(acc[m][n8][r] / l_i[m][r]);
            }
}

// ============================================================
// host launch
// ============================================================
extern "C" void kernel_launch(void* const* d_in, const int* in_sizes, int n_in,
                              void* d_out, int out_size, void* d_ws, size_t ws_size,
                              hipStream_t stream) {
    const float* v_in  = (const float*)d_in[0];
    const float* xeps  = (const float*)d_in[1];
    const float* fcos  = (const float*)d_in[2];
    const float* fsin  = (const float*)d_in[3];
    const float* Wea   = (const float*)d_in[4];
    const float* Wa    = (const float*)d_in[5];
    const float* Wp    = (const float*)d_in[6];
    const float* Wep   = (const float*)d_in[7];
    float* out = (float*)d_out;

    char* ws = (char*)d_ws;
    unsigned short* xe16 = (unsigned short*)ws;  ws += (size_t)MROWS * KDIM * 2;
    unsigned short* v16  = (unsigned short*)ws;  ws += (size_t)MROWS * KDIM * 2;
    unsigned short* WeaT = (unsigned short*)ws;  ws += (size_t)NQK * KDIM * 2;
    unsigned short* WaT  = (unsigned short*)ws;  ws += (size_t)KDIM * KDIM * 2;
    unsigned short* WpT  = (unsigned short*)ws;  ws += (size_t)KDIM * KDIM * 2;
    unsigned short* WepT = (unsigned short*)ws;  ws += (size_t)KDIM * KDIM * 2;
    unsigned short* qk16 = (unsigned short*)ws;  ws += (size_t)MROWS * NQK * 2;
    unsigned short* vp16 = (unsigned short*)ws;  ws += (size_t)MROWS * KDIM * 2;
    unsigned short* y16  = (unsigned short*)ws;  ws += (size_t)MROWS * KDIM * 2;
    unsigned short* vpT  = v16;   // v16 dead after vp GEMM; reuse

    // 1. casts
    cast_f32_bf16<<<8192, 256, 0, stream>>>(xeps, xe16, MROWS * KDIM / 4);
    cast_f32_bf16<<<8192, 256, 0, stream>>>(v_in, v16,  MROWS * KDIM / 4);

    // 2. weight transpose-casts
    transpose_cast<<<dim3(NQK / 32, KDIM / 32), dim3(32, 8), 0, stream>>>(Wea, WeaT, KDIM, NQK);
    transpose_cast<<<dim3(KDIM / 32, KDIM / 32), dim3(32, 8), 0, stream>>>(Wa,  WaT,  KDIM, KDIM);
    transpose_cast<<<dim3(KDIM / 32, KDIM / 32), dim3(32, 8), 0, stream>>>(Wp,  WpT,  KDIM, KDIM);
    transpose_cast<<<dim3(KDIM / 32, KDIM / 32), dim3(32, 8), 0, stream>>>(Wep, WepT, KDIM, KDIM);

    // 3. qk = xe16 @ WeaT  (bf16 out) : 16x16 tiles = 256 blocks
    gemm256<<<256, 512, 0, stream>>>(
        xe16, WeaT, nullptr, qk16, NQK, 16, 256, 1,
        xe16, WeaT, nullptr, qk16, NQK, 16, 1, KDIM);

    // 4. RoPE
    rope_kernel<<<8192, 256, 0, stream>>>(qk16, fcos, fsin);

    // 5. grouped: vp = v16 @ WaT (bf16) + x_eps_out = xe16 @ WepT (f32)
    gemm256<<<256, 512, 0, stream>>>(
        v16,  WaT,  nullptr, vp16, KDIM, 8, 128, 1,
        xe16, WepT, out + (size_t)MROWS * KDIM, nullptr, KDIM, 8, 0, KDIM);

    // 5b. transpose vp -> vpT [bh][d][t]
    transpose_v<<<dim3(1024 / 32, 8192 / 32), dim3(32, 8), 0, stream>>>(vp16, vpT);

    // 6. attention -> y16
    attn_kernel<<<dim3(64, 8), 256, 0, stream>>>(qk16, vpT, y16);

    // 7. v_out = y16 @ WpT (f32 out)
    gemm256<<<128, 512, 0, stream>>>(
        y16, WpT, out, nullptr, KDIM, 8, 128, 0,
        y16, WpT, out, nullptr, KDIM, 8, 0, KDIM);
}